// Round 7
// baseline (1958.677 us; speedup 1.0000x reference)
//
#include <hip/hip_runtime.h>

#define N_NODES 100000
#define N_EDGES 6400000
#define FEAT 39   // 3 + 9 + 27
#define HID 256
#define OUT 64
#define NB 8      // nodes per block in MLP

// ---------------- binned-strip path parameters ------------------------------
#define G_BUCKETS 625          // coarse buckets
#define BNODES    160          // nodes per bucket (625*160 = 100000 exactly)
#define NWG1      160          // pass-1 workgroups
#define EPW       (N_EDGES / NWG1)   // 40000 edges per WG
#define PAD       120          // strip capacity: Poisson(62.5), P(>=120)~1e-9/cell

// ---------------- workspace layout (bytes) ----------------------------------
// Shared by all paths:
//   xl : N x 4  f32 @ 0 ; h1 : N x 12 f32 ; h2 : N x 28 f32
#define OFF_XL     0
#define OFF_H1     ((size_t)N_NODES * 16)                      // 1,600,000
#define OFF_H2     (OFF_H1 + (size_t)N_NODES * 48)             // 6,400,000
// bin path:
#define OFF_CNTS   (OFF_H2 + (size_t)N_NODES * 112)            // 17,600,000: [G][NWG1] int
#define OFF_STRIPS (((OFF_CNTS + (size_t)G_BUCKETS * NWG1 * 4) + 255) & ~(size_t)255)
#define WS_BIN_NEEDED (OFF_STRIPS + (size_t)NWG1 * G_BUCKETS * PAD * 16)
// legacy CSR paths (fallback):
#define OFF_STARTS (OFF_H2 + (size_t)N_NODES * 112)
#define OFF_CNT    (OFF_STARTS + ((size_t)N_NODES + 1) * 4 + 124)
#define OFF_KVP    ((OFF_CNT + (size_t)N_NODES * 4 + 255) & ~(size_t)255)
#define CAPD 144
#define WS_NEEDED      (OFF_KVP + (size_t)N_EDGES * 16)
#define WS_CAP_NEEDED  (OFF_KVP + (size_t)N_NODES * CAPD * 16)

// ---------------- kernel 1: xl[n,i] = sum_j gauges[n,j,i] * x[n,j] ----------
__global__ void xl_kernel(const float* __restrict__ x,
                          const float* __restrict__ gauges,
                          float* __restrict__ xl) {
    int n = blockIdx.x * blockDim.x + threadIdx.x;
    if (n >= N_NODES) return;
    float x0 = x[n * 3 + 0], x1 = x[n * 3 + 1], x2 = x[n * 3 + 2];
    const float* g = gauges + n * 9;
    float4 o;
    o.x = g[0] * x0 + g[3] * x1 + g[6] * x2;
    o.y = g[1] * x0 + g[4] * x1 + g[7] * x2;
    o.z = g[2] * x0 + g[5] * x1 + g[8] * x2;
    o.w = 0.f;
    ((float4*)xl)[n] = o;
}

// ---------------- pass 1: bin edges into private per-(WG,bucket) strips -----
// strip (w,b) is written ONLY by WG w -> same XCD -> L2 write-combines full lines.
__global__ __launch_bounds__(256) void bin_kernel(const int* __restrict__ ei,
                                                  const float* __restrict__ kv,
                                                  float4* __restrict__ strips,
                                                  int* __restrict__ counts) {
    __shared__ int cur[G_BUCKETS];
    int w = blockIdx.x, t = threadIdx.x;
    for (int b = t; b < G_BUCKETS; b += 256) cur[b] = 0;
    __syncthreads();
    int e0 = w * EPW;
    for (int e = e0 + t; e < e0 + EPW; e += 256) {
        int s = ei[e];
        int d = ei[N_EDGES + e];
        int b = d / BNODES;
        int dl = d - b * BNODES;           // 0..159
        float4 p;
        p.x = kv[e];
        p.y = kv[N_EDGES + e];
        p.z = kv[2 * N_EDGES + e];
        p.w = __int_as_float(s | (dl << 17));   // src<2^17, dl<2^8
        int slot = atomicAdd(&cur[b], 1);
        if (slot < PAD)
            strips[((size_t)w * G_BUCKETS + b) * PAD + slot] = p;
    }
    __syncthreads();
    for (int b = t; b < G_BUCKETS; b += 256) {
        int c = cur[b];
        counts[(size_t)b * NWG1 + w] = c < PAD ? c : PAD;   // [b][w] for coalesced pass-2 load
    }
}

// ---------------- pass 2a: conv1 fused, one WG per bucket, LDS atomics ------
__global__ __launch_bounds__(256) void conv1_fused(const float4* __restrict__ strips,
                                                   const int* __restrict__ counts,
                                                   const float4* __restrict__ xl,
                                                   float* __restrict__ h1) {
    __shared__ float hl[BNODES][9];
    __shared__ int pfx[NWG1 + 1];
    __shared__ int cnts[NWG1];
    int b = blockIdx.x, t = threadIdx.x;
    for (int i = t; i < BNODES * 9; i += 256) hl[i / 9][i % 9] = 0.f;
    if (t < NWG1) cnts[t] = counts[(size_t)b * NWG1 + t];
    __syncthreads();
    if (t == 0) {
        int run = 0;
        pfx[0] = 0;
        for (int w = 0; w < NWG1; ++w) { run += cnts[w]; pfx[w + 1] = run; }
    }
    __syncthreads();
    int total = pfx[NWG1];
    for (int j = t; j < total; j += 256) {
        int lo = 0, hi = NWG1;                 // pfx[lo] <= j < pfx[hi]
        while (hi - lo > 1) { int mid = (lo + hi) >> 1; if (pfx[mid] <= j) lo = mid; else hi = mid; }
        int idx = j - pfx[lo];
        float4 p = strips[((size_t)lo * G_BUCKETS + b) * PAD + idx];
        unsigned pw = __float_as_uint(p.w);
        int s  = pw & 0x1FFFF;
        int dl = pw >> 17;
        float4 xs = xl[s];
        atomicAdd(&hl[dl][0], p.x * xs.x);
        atomicAdd(&hl[dl][1], p.y * xs.x);
        atomicAdd(&hl[dl][2], p.z * xs.x);
        atomicAdd(&hl[dl][3], p.x * xs.y);
        atomicAdd(&hl[dl][4], p.y * xs.y);
        atomicAdd(&hl[dl][5], p.z * xs.y);
        atomicAdd(&hl[dl][6], p.x * xs.z);
        atomicAdd(&hl[dl][7], p.y * xs.z);
        atomicAdd(&hl[dl][8], p.z * xs.z);
    }
    __syncthreads();
    int nbase = b * BNODES;
    for (int i = t; i < BNODES * 9; i += 256) {
        int m = i / 9, c = i % 9;
        h1[(size_t)(nbase + m) * 12 + c] = hl[m][c];
    }
}

// ---------------- pass 2b: conv2 fused, one WG per bucket, LDS atomics ------
__global__ __launch_bounds__(256) void conv2_fused(const float4* __restrict__ strips,
                                                   const int* __restrict__ counts,
                                                   const float* __restrict__ h1,
                                                   float* __restrict__ h2) {
    __shared__ float hl[BNODES][27];
    __shared__ int pfx[NWG1 + 1];
    __shared__ int cnts[NWG1];
    int b = blockIdx.x, t = threadIdx.x;
    for (int i = t; i < BNODES * 27; i += 256) hl[i / 27][i % 27] = 0.f;
    if (t < NWG1) cnts[t] = counts[(size_t)b * NWG1 + t];
    __syncthreads();
    if (t == 0) {
        int run = 0;
        pfx[0] = 0;
        for (int w = 0; w < NWG1; ++w) { run += cnts[w]; pfx[w + 1] = run; }
    }
    __syncthreads();
    int total = pfx[NWG1];
    for (int j = t; j < total; j += 256) {
        int lo = 0, hi = NWG1;
        while (hi - lo > 1) { int mid = (lo + hi) >> 1; if (pfx[mid] <= j) lo = mid; else hi = mid; }
        int idx = j - pfx[lo];
        float4 p = strips[((size_t)lo * G_BUCKETS + b) * PAD + idx];
        unsigned pw = __float_as_uint(p.w);
        int s  = pw & 0x1FFFF;
        int dl = pw >> 17;
        const float4* hs = (const float4*)(h1 + (size_t)s * 12);
        float4 v0 = hs[0], v1 = hs[1], v2 = hs[2];
        float h[9] = {v0.x, v0.y, v0.z, v0.w, v1.x, v1.y, v1.z, v1.w, v2.x};
#pragma unroll
        for (int c = 0; c < 9; ++c) {
            atomicAdd(&hl[dl][c * 3 + 0], p.x * h[c]);
            atomicAdd(&hl[dl][c * 3 + 1], p.y * h[c]);
            atomicAdd(&hl[dl][c * 3 + 2], p.z * h[c]);
        }
    }
    __syncthreads();
    int nbase = b * BNODES;
    for (int i = t; i < BNODES * 27; i += 256) {
        int m = i / 27, c = i % 27;
        h2[(size_t)(nbase + m) * 28 + c] = hl[m][c];
    }
}

// ---------------- legacy capacity-CSR path (fallback, proven 758us) ---------
__global__ void scatter_cap_kernel(const int* __restrict__ ei,
                                   const float* __restrict__ kv,
                                   int* __restrict__ cnt,
                                   float4* __restrict__ kvp) {
    int e = blockIdx.x * blockDim.x + threadIdx.x;
    if (e >= N_EDGES) return;
    int s = ei[e];
    int d = ei[N_EDGES + e];
    float4 p;
    p.x = kv[e];
    p.y = kv[N_EDGES + e];
    p.z = kv[2 * N_EDGES + e];
    p.w = __int_as_float(s);
    int pos = atomicAdd(&cnt[d], 1);
    if (pos < CAPD) kvp[(size_t)d * CAPD + pos] = p;
}

template <bool CAP_MODE>
__global__ __launch_bounds__(256) void conv1_kernel(const int* __restrict__ starts,
                                                    const int* __restrict__ cnt,
                                                    const float4* __restrict__ kvp,
                                                    const float4* __restrict__ xl,
                                                    float* __restrict__ h1) {
    int gid = blockIdx.x * blockDim.x + threadIdx.x;
    int wid = gid >> 6, lane = gid & 63;
    if (wid >= N_NODES) return;
    int st, en;
    if (CAP_MODE) {
        st = wid * CAPD;
        int c = cnt[wid]; if (c > CAPD) c = CAPD;
        en = st + c;
    } else {
        st = starts[wid]; en = starts[wid + 1];
    }
    float a[9];
#pragma unroll
    for (int c = 0; c < 9; ++c) a[c] = 0.f;
    for (int i = st + lane; i < en; i += 64) {
        float4 p = kvp[i];
        float4 xs = xl[__float_as_int(p.w)];
        a[0] += p.x * xs.x; a[1] += p.y * xs.x; a[2] += p.z * xs.x;
        a[3] += p.x * xs.y; a[4] += p.y * xs.y; a[5] += p.z * xs.y;
        a[6] += p.x * xs.z; a[7] += p.y * xs.z; a[8] += p.z * xs.z;
    }
#pragma unroll
    for (int off = 32; off > 0; off >>= 1) {
#pragma unroll
        for (int c = 0; c < 9; ++c) a[c] += __shfl_xor(a[c], off, 64);
    }
    if (lane == 0) {
        float* r = h1 + (size_t)wid * 12;
        ((float4*)r)[0] = make_float4(a[0], a[1], a[2], a[3]);
        ((float4*)r)[1] = make_float4(a[4], a[5], a[6], a[7]);
        ((float4*)r)[2] = make_float4(a[8], 0.f, 0.f, 0.f);
    }
}

template <bool CAP_MODE>
__global__ __launch_bounds__(256) void conv2_kernel(const int* __restrict__ starts,
                                                    const int* __restrict__ cnt,
                                                    const float4* __restrict__ kvp,
                                                    const float* __restrict__ h1,
                                                    float* __restrict__ h2) {
    int gid = blockIdx.x * blockDim.x + threadIdx.x;
    int wid = gid >> 6, lane = gid & 63;
    if (wid >= N_NODES) return;
    int st, en;
    if (CAP_MODE) {
        st = wid * CAPD;
        int c = cnt[wid]; if (c > CAPD) c = CAPD;
        en = st + c;
    } else {
        st = starts[wid]; en = starts[wid + 1];
    }
    float a[27];
#pragma unroll
    for (int c = 0; c < 27; ++c) a[c] = 0.f;
    for (int i = st + lane; i < en; i += 64) {
        float4 p = kvp[i];
        const float4* hs = (const float4*)(h1 + (size_t)__float_as_int(p.w) * 12);
        float4 v0 = hs[0], v1 = hs[1], v2 = hs[2];
        float h[9] = {v0.x, v0.y, v0.z, v0.w, v1.x, v1.y, v1.z, v1.w, v2.x};
#pragma unroll
        for (int c = 0; c < 9; ++c) {
            a[c * 3 + 0] += p.x * h[c];
            a[c * 3 + 1] += p.y * h[c];
            a[c * 3 + 2] += p.z * h[c];
        }
    }
#pragma unroll
    for (int off = 32; off > 0; off >>= 1) {
#pragma unroll
        for (int c = 0; c < 27; ++c) a[c] += __shfl_xor(a[c], off, 64);
    }
    if (lane == 0) {
        float* r = h2 + (size_t)wid * 28;
#pragma unroll
        for (int q = 0; q < 6; ++q)
            ((float4*)r)[q] = make_float4(a[q*4], a[q*4+1], a[q*4+2], a[q*4+3]);
        ((float4*)r)[6] = make_float4(a[24], a[25], a[26], 0.f);
    }
}

// ---------------- last-resort atomic fallback -------------------------------
__global__ void edge1_atomic(const int* __restrict__ ei,
                             const float* __restrict__ kv,
                             const float* __restrict__ xl,
                             float* __restrict__ h1) {
    int e = blockIdx.x * blockDim.x + threadIdx.x;
    if (e >= N_EDGES) return;
    int s = ei[e], d = ei[N_EDGES + e];
    float k0 = kv[e], k1 = kv[N_EDGES + e], k2 = kv[2 * N_EDGES + e];
    const float* xs = xl + (size_t)s * 4;
    float* hd = h1 + (size_t)d * 12;
#pragma unroll
    for (int c = 0; c < 3; ++c) {
        float v = xs[c];
        atomicAdd(hd + c * 3 + 0, k0 * v);
        atomicAdd(hd + c * 3 + 1, k1 * v);
        atomicAdd(hd + c * 3 + 2, k2 * v);
    }
}

__global__ void edge2_atomic(const int* __restrict__ ei,
                             const float* __restrict__ kv,
                             const float* __restrict__ h1,
                             float* __restrict__ h2) {
    int e = blockIdx.x * blockDim.x + threadIdx.x;
    if (e >= N_EDGES) return;
    int s = ei[e], d = ei[N_EDGES + e];
    float k0 = kv[e], k1 = kv[N_EDGES + e], k2 = kv[2 * N_EDGES + e];
    const float* hs = h1 + (size_t)s * 12;
    float* hd = h2 + (size_t)d * 28;
#pragma unroll
    for (int c = 0; c < 9; ++c) {
        float v = hs[c];
        atomicAdd(hd + c * 3 + 0, k0 * v);
        atomicAdd(hd + c * 3 + 1, k1 * v);
        atomicAdd(hd + c * 3 + 2, k2 * v);
    }
}

// ---------------- MLP 39 -> 256 (relu) -> 64 --------------------------------
__global__ __launch_bounds__(256) void mlp_kernel(const float* __restrict__ xl,
                                                  const float* __restrict__ h1,
                                                  const float* __restrict__ h2,
                                                  const float* __restrict__ W1,
                                                  const float* __restrict__ b1,
                                                  const float* __restrict__ W2,
                                                  const float* __restrict__ b2,
                                                  float* __restrict__ out) {
    __shared__ float f[NB][FEAT + 1];
    __shared__ float hmid[NB][HID];
    __shared__ float partial[4][NB][OUT];

    int t = threadIdx.x;
    int base = blockIdx.x * NB;

    for (int i = t; i < NB * FEAT; i += 256) {
        int m = i / FEAT, k = i % FEAT;
        int n = base + m;
        float v = 0.f;
        if (n < N_NODES) {
            if (k < 3)       v = xl[(size_t)n * 4 + k];
            else if (k < 12) v = h1[(size_t)n * 12 + (k - 3)];
            else             v = h2[(size_t)n * 28 + (k - 12)];
        }
        f[m][k] = v;
    }
    __syncthreads();

    float acc[NB];
    float bb = b1[t];
#pragma unroll
    for (int m = 0; m < NB; ++m) acc[m] = bb;
#pragma unroll
    for (int k = 0; k < FEAT; ++k) {
        float w = W1[k * HID + t];
#pragma unroll
        for (int m = 0; m < NB; ++m) acc[m] += f[m][k] * w;
    }
#pragma unroll
    for (int m = 0; m < NB; ++m) hmid[m][t] = fmaxf(acc[m], 0.f);
    __syncthreads();

    int o = t & 63, q = t >> 6;
    float p[NB];
#pragma unroll
    for (int m = 0; m < NB; ++m) p[m] = 0.f;
    for (int hh = 0; hh < 64; ++hh) {
        int h = q * 64 + hh;
        float w = W2[h * OUT + o];
#pragma unroll
        for (int m = 0; m < NB; ++m) p[m] += hmid[m][h] * w;
    }
#pragma unroll
    for (int m = 0; m < NB; ++m) partial[q][m][o] = p[m];
    __syncthreads();

    if (t < OUT) {
        float bo = b2[t];
        for (int m = 0; m < NB; ++m) {
            int n = base + m;
            if (n < N_NODES) {
                out[n * OUT + t] = partial[0][m][t] + partial[1][m][t] +
                                   partial[2][m][t] + partial[3][m][t] + bo;
            }
        }
    }
}

extern "C" void kernel_launch(void* const* d_in, const int* in_sizes, int n_in,
                              void* d_out, int out_size, void* d_ws, size_t ws_size,
                              hipStream_t stream) {
    const float* x      = (const float*)d_in[0];
    const float* gauges = (const float*)d_in[1];
    const float* kv     = (const float*)d_in[2];
    const float* W1     = (const float*)d_in[3];
    const float* b1     = (const float*)d_in[4];
    const float* W2     = (const float*)d_in[5];
    const float* b2     = (const float*)d_in[6];
    const int*   ei     = (const int*)d_in[7];
    float* out = (float*)d_out;

    char* ws = (char*)d_ws;
    float*  xl     = (float*)(ws + OFF_XL);
    float*  h1     = (float*)(ws + OFF_H1);
    float*  h2     = (float*)(ws + OFF_H2);

    const int EB = (N_EDGES + 255) / 256;
    const int CB = (N_NODES * 64 + 255) / 256;

    xl_kernel<<<(N_NODES + 255) / 256, 256, 0, stream>>>(x, gauges, xl);

    if (ws_size >= WS_BIN_NEEDED) {
        // -------- binned strips + LDS-atomic fused convs --------
        int*    counts = (int*)(ws + OFF_CNTS);
        float4* strips = (float4*)(ws + OFF_STRIPS);
        bin_kernel<<<NWG1, 256, 0, stream>>>(ei, kv, strips, counts);
        conv1_fused<<<G_BUCKETS, 256, 0, stream>>>(strips, counts, (const float4*)xl, h1);
        conv2_fused<<<G_BUCKETS, 256, 0, stream>>>(strips, counts, h1, h2);
    } else if (ws_size >= WS_CAP_NEEDED) {
        // -------- capacity-CSR (proven Round 6: 758 us) --------
        int*    cnt = (int*)(ws + OFF_CNT);
        float4* kvp = (float4*)(ws + OFF_KVP);
        int*    starts = (int*)(ws + OFF_STARTS);
        hipMemsetAsync(cnt, 0, (size_t)N_NODES * 4, stream);
        scatter_cap_kernel<<<EB, 256, 0, stream>>>(ei, kv, cnt, kvp);
        conv1_kernel<true><<<CB, 256, 0, stream>>>(starts, cnt, kvp, (const float4*)xl, h1);
        conv2_kernel<true><<<CB, 256, 0, stream>>>(starts, cnt, kvp, h1, h2);
    } else {
        // -------- last resort: global float atomics (proven Round 2) --------
        hipMemsetAsync(h1, 0, (size_t)N_NODES * (48 + 112), stream);
        edge1_atomic<<<EB, 256, 0, stream>>>(ei, kv, xl, h1);
        edge2_atomic<<<EB, 256, 0, stream>>>(ei, kv, h1, h2);
    }

    mlp_kernel<<<(N_NODES + NB - 1) / NB, 256, 0, stream>>>(xl, h1, h2, W1, b1, W2, b2, out);
}

// Round 9
// 1664.272 us; speedup vs baseline: 1.1769x; 1.1769x over previous
//
#include <hip/hip_runtime.h>

#define N_NODES 100000
#define N_EDGES 6400000
#define FEAT 39   // 3 + 9 + 27
#define HID 256
#define OUT 64
#define NB 8      // nodes per block in MLP

// ---------------- strips path parameters ------------------------------------
#define NBKT  2000             // fine buckets
#define BKN   50               // nodes per bucket (2000*50 = 100000 exactly)
#define NSETS 8                // strip sets, keyed by blockIdx&7 (~XCD)
#define PAD1  520              // cell capacity: Poisson(400) + 6 sigma
#define P1_WGS 1024
#define EPW1  (N_EDGES / P1_WGS)   // 6250 edges per WG, exact

// ---------------- workspace layout (bytes) ----------------------------------
// xl : N x 4 f32 @0 ; h1 : N x 12 f32 ; h2 : N x 28 f32
#define OFF_XL  0
#define OFF_H1  ((size_t)N_NODES * 16)
#define OFF_H2  (OFF_H1 + (size_t)N_NODES * 48)
#define OFF_CUR (OFF_H2 + (size_t)N_NODES * 112)                 // [NSETS*NBKT] int
#define OFF_STR ((OFF_CUR + (size_t)NSETS * NBKT * 4 + 255) & ~(size_t)255)
#define WS_STRIPS_NEEDED (OFF_STR + (size_t)NSETS * NBKT * PAD1 * 16)   // ~151 MB

// ---------------- kernel 1: xl[n,i] = sum_j gauges[n,j,i] * x[n,j] ----------
__global__ void xl_kernel(const float* __restrict__ x,
                          const float* __restrict__ gauges,
                          float* __restrict__ xl) {
    int n = blockIdx.x * blockDim.x + threadIdx.x;
    if (n >= N_NODES) return;
    float x0 = x[n * 3 + 0], x1 = x[n * 3 + 1], x2 = x[n * 3 + 2];
    const float* g = gauges + n * 9;
    float4 o;
    o.x = g[0] * x0 + g[3] * x1 + g[6] * x2;
    o.y = g[1] * x0 + g[4] * x1 + g[7] * x2;
    o.z = g[2] * x0 + g[5] * x1 + g[8] * x2;
    o.w = 0.f;
    ((float4*)xl)[n] = o;
}

// ---------------- bin: edges -> per-(set,bucket) strips ---------------------
// set = blockIdx&7 ~ XCD (perf heuristic only): the 4 winners of each 64B
// strip line come from one XCD's L2 -> full-line write-back.
__global__ __launch_bounds__(256) void bin_kernel(const int* __restrict__ ei,
                                                  const float* __restrict__ kv,
                                                  int* __restrict__ cur,
                                                  float4* __restrict__ strips) {
    int w = blockIdx.x, t = threadIdx.x;
    int s = w & (NSETS - 1);
    int e0 = w * EPW1;
    for (int e = e0 + t; e < e0 + EPW1; e += 256) {
        int src = ei[e];
        int d   = ei[N_EDGES + e];
        int b   = d / BKN;
        int dl  = d - b * BKN;             // 0..49
        float4 p;
        p.x = kv[e];
        p.y = kv[N_EDGES + e];
        p.z = kv[2 * N_EDGES + e];
        p.w = __int_as_float(src | (dl << 17));   // src < 2^17, dl < 2^6
        int cell = s * NBKT + b;
        int slot = atomicAdd(&cur[cell], 1);
        if (slot < PAD1) strips[(size_t)cell * PAD1 + slot] = p;
    }
}

// ---------------- conv1: 3ch -> 9ch, one WG per bucket ----------------------
__global__ __launch_bounds__(256) void conv1_direct(const int* __restrict__ cur,
                                                    const float4* __restrict__ strips,
                                                    const float4* __restrict__ xl,
                                                    float* __restrict__ h1) {
    __shared__ float hl[BKN][9];
    __shared__ int pfx[NSETS + 1];
    int b = blockIdx.x, t = threadIdx.x;
    for (int i = t; i < BKN * 9; i += 256) hl[i / 9][i % 9] = 0.f;
    if (t == 0) {
        int run = 0;
        for (int s = 0; s < NSETS; ++s) {
            pfx[s] = run;
            int c = cur[s * NBKT + b];
            run += (c < PAD1 ? c : PAD1);
        }
        pfx[NSETS] = run;
    }
    __syncthreads();
    int total = pfx[NSETS];
    for (int j = t; j < total; j += 256) {
        int s = 0;
#pragma unroll
        for (int k = 1; k < NSETS; ++k) s += (j >= pfx[k]);
        int idx = j - pfx[s];
        float4 p = strips[((size_t)(s * NBKT + b)) * PAD1 + idx];
        unsigned pw = __float_as_uint(p.w);
        int src = pw & 0x1FFFF;
        int dl  = pw >> 17;
        float4 xs = xl[src];
        atomicAdd(&hl[dl][0], p.x * xs.x);
        atomicAdd(&hl[dl][1], p.y * xs.x);
        atomicAdd(&hl[dl][2], p.z * xs.x);
        atomicAdd(&hl[dl][3], p.x * xs.y);
        atomicAdd(&hl[dl][4], p.y * xs.y);
        atomicAdd(&hl[dl][5], p.z * xs.y);
        atomicAdd(&hl[dl][6], p.x * xs.z);
        atomicAdd(&hl[dl][7], p.y * xs.z);
        atomicAdd(&hl[dl][8], p.z * xs.z);
    }
    __syncthreads();
    int nbase = b * BKN;
    for (int i = t; i < BKN * 9; i += 256) {
        int m = i / 9, c = i % 9;
        h1[(size_t)(nbase + m) * 12 + c] = hl[m][c];
    }
}

// ---------------- conv2: 9ch -> 27ch, one WG per bucket ---------------------
__global__ __launch_bounds__(256) void conv2_direct(const int* __restrict__ cur,
                                                    const float4* __restrict__ strips,
                                                    const float* __restrict__ h1,
                                                    float* __restrict__ h2) {
    __shared__ float hl[BKN][27];
    __shared__ int pfx[NSETS + 1];
    int b = blockIdx.x, t = threadIdx.x;
    for (int i = t; i < BKN * 27; i += 256) hl[i / 27][i % 27] = 0.f;
    if (t == 0) {
        int run = 0;
        for (int s = 0; s < NSETS; ++s) {
            pfx[s] = run;
            int c = cur[s * NBKT + b];
            run += (c < PAD1 ? c : PAD1);
        }
        pfx[NSETS] = run;
    }
    __syncthreads();
    int total = pfx[NSETS];
    for (int j = t; j < total; j += 256) {
        int s = 0;
#pragma unroll
        for (int k = 1; k < NSETS; ++k) s += (j >= pfx[k]);
        int idx = j - pfx[s];
        float4 p = strips[((size_t)(s * NBKT + b)) * PAD1 + idx];
        unsigned pw = __float_as_uint(p.w);
        int src = pw & 0x1FFFF;
        int dl  = pw >> 17;
        const float4* hs = (const float4*)(h1 + (size_t)src * 12);
        float4 v0 = hs[0], v1 = hs[1], v2 = hs[2];
        float h[9] = {v0.x, v0.y, v0.z, v0.w, v1.x, v1.y, v1.z, v1.w, v2.x};
#pragma unroll
        for (int c = 0; c < 9; ++c) {
            atomicAdd(&hl[dl][c * 3 + 0], p.x * h[c]);
            atomicAdd(&hl[dl][c * 3 + 1], p.y * h[c]);
            atomicAdd(&hl[dl][c * 3 + 2], p.z * h[c]);
        }
    }
    __syncthreads();
    int nbase = b * BKN;
    for (int i = t; i < BKN * 27; i += 256) {
        int m = i / 27, c = i % 27;
        h2[(size_t)(nbase + m) * 28 + c] = hl[m][c];
    }
}

// ---------------- last-resort atomic fallback (small ws) --------------------
__global__ void edge1_atomic(const int* __restrict__ ei,
                             const float* __restrict__ kv,
                             const float* __restrict__ xl,
                             float* __restrict__ h1) {
    int e = blockIdx.x * blockDim.x + threadIdx.x;
    if (e >= N_EDGES) return;
    int s = ei[e], d = ei[N_EDGES + e];
    float k0 = kv[e], k1 = kv[N_EDGES + e], k2 = kv[2 * N_EDGES + e];
    const float* xs = xl + (size_t)s * 4;
    float* hd = h1 + (size_t)d * 12;
#pragma unroll
    for (int c = 0; c < 3; ++c) {
        float v = xs[c];
        atomicAdd(hd + c * 3 + 0, k0 * v);
        atomicAdd(hd + c * 3 + 1, k1 * v);
        atomicAdd(hd + c * 3 + 2, k2 * v);
    }
}

__global__ void edge2_atomic(const int* __restrict__ ei,
                             const float* __restrict__ kv,
                             const float* __restrict__ h1,
                             float* __restrict__ h2) {
    int e = blockIdx.x * blockDim.x + threadIdx.x;
    if (e >= N_EDGES) return;
    int s = ei[e], d = ei[N_EDGES + e];
    float k0 = kv[e], k1 = kv[N_EDGES + e], k2 = kv[2 * N_EDGES + e];
    const float* hs = h1 + (size_t)s * 12;
    float* hd = h2 + (size_t)d * 28;
#pragma unroll
    for (int c = 0; c < 9; ++c) {
        float v = hs[c];
        atomicAdd(hd + c * 3 + 0, k0 * v);
        atomicAdd(hd + c * 3 + 1, k1 * v);
        atomicAdd(hd + c * 3 + 2, k2 * v);
    }
}

// ---------------- MLP 39 -> 256 (relu) -> 64 --------------------------------
__global__ __launch_bounds__(256) void mlp_kernel(const float* __restrict__ xl,
                                                  const float* __restrict__ h1,
                                                  const float* __restrict__ h2,
                                                  const float* __restrict__ W1,
                                                  const float* __restrict__ b1,
                                                  const float* __restrict__ W2,
                                                  const float* __restrict__ b2,
                                                  float* __restrict__ out) {
    __shared__ float f[NB][FEAT + 1];
    __shared__ float hmid[NB][HID];
    __shared__ float partial[4][NB][OUT];

    int t = threadIdx.x;
    int base = blockIdx.x * NB;

    for (int i = t; i < NB * FEAT; i += 256) {
        int m = i / FEAT, k = i % FEAT;
        int n = base + m;
        float v = 0.f;
        if (n < N_NODES) {
            if (k < 3)       v = xl[(size_t)n * 4 + k];
            else if (k < 12) v = h1[(size_t)n * 12 + (k - 3)];
            else             v = h2[(size_t)n * 28 + (k - 12)];
        }
        f[m][k] = v;
    }
    __syncthreads();

    float acc[NB];
    float bb = b1[t];
#pragma unroll
    for (int m = 0; m < NB; ++m) acc[m] = bb;
#pragma unroll
    for (int k = 0; k < FEAT; ++k) {
        float w = W1[k * HID + t];
#pragma unroll
        for (int m = 0; m < NB; ++m) acc[m] += f[m][k] * w;
    }
#pragma unroll
    for (int m = 0; m < NB; ++m) hmid[m][t] = fmaxf(acc[m], 0.f);
    __syncthreads();

    int o = t & 63, q = t >> 6;
    float p[NB];
#pragma unroll
    for (int m = 0; m < NB; ++m) p[m] = 0.f;
    for (int hh = 0; hh < 64; ++hh) {
        int h = q * 64 + hh;
        float w = W2[h * OUT + o];
#pragma unroll
        for (int m = 0; m < NB; ++m) p[m] += hmid[m][h] * w;
    }
#pragma unroll
    for (int m = 0; m < NB; ++m) partial[q][m][o] = p[m];
    __syncthreads();

    if (t < OUT) {
        float bo = b2[t];
        for (int m = 0; m < NB; ++m) {
            int n = base + m;
            if (n < N_NODES) {
                out[n * OUT + t] = partial[0][m][t] + partial[1][m][t] +
                                   partial[2][m][t] + partial[3][m][t] + bo;
            }
        }
    }
}

extern "C" void kernel_launch(void* const* d_in, const int* in_sizes, int n_in,
                              void* d_out, int out_size, void* d_ws, size_t ws_size,
                              hipStream_t stream) {
    const float* x      = (const float*)d_in[0];
    const float* gauges = (const float*)d_in[1];
    const float* kv     = (const float*)d_in[2];
    const float* W1     = (const float*)d_in[3];
    const float* b1     = (const float*)d_in[4];
    const float* W2     = (const float*)d_in[5];
    const float* b2     = (const float*)d_in[6];
    const int*   ei     = (const int*)d_in[7];
    float* out = (float*)d_out;

    char* ws = (char*)d_ws;
    float* xl = (float*)(ws + OFF_XL);
    float* h1 = (float*)(ws + OFF_H1);
    float* h2 = (float*)(ws + OFF_H2);

    const int EB = (N_EDGES + 255) / 256;

    xl_kernel<<<(N_NODES + 255) / 256, 256, 0, stream>>>(x, gauges, xl);

    if (ws_size >= WS_STRIPS_NEEDED) {
        // -------- XCD-set strips + direct LDS-accumulate convs --------
        int*    cur    = (int*)(ws + OFF_CUR);
        float4* strips = (float4*)(ws + OFF_STR);
        hipMemsetAsync(cur, 0, (size_t)NSETS * NBKT * 4, stream);
        bin_kernel<<<P1_WGS, 256, 0, stream>>>(ei, kv, cur, strips);
        conv1_direct<<<NBKT, 256, 0, stream>>>(cur, strips, (const float4*)xl, h1);
        conv2_direct<<<NBKT, 256, 0, stream>>>(cur, strips, h1, h2);
    } else {
        // -------- last resort: global float atomics (proven Round 2) --------
        hipMemsetAsync(h1, 0, (size_t)N_NODES * (48 + 112), stream);
        edge1_atomic<<<EB, 256, 0, stream>>>(ei, kv, xl, h1);
        edge2_atomic<<<EB, 256, 0, stream>>>(ei, kv, h1, h2);
    }

    mlp_kernel<<<(N_NODES + NB - 1) / NB, 256, 0, stream>>>(xl, h1, h2, W1, b1, W2, b2, out);
}

// Round 10
// 798.018 us; speedup vs baseline: 2.4544x; 2.0855x over previous
//
#include <hip/hip_runtime.h>

#define N_NODES 100000
#define N_EDGES 6400000
#define FEAT 39   // 3 + 9 + 27
#define HID 256
#define OUT 64
#define NB 8      // nodes per block in MLP

// ---------------- strips path parameters ------------------------------------
#define NBKT  2000             // buckets
#define BKN   50               // nodes per bucket (2000*50 = 100000 exactly)
#define NSETS 8                // strip sets, keyed by blockIdx&7 (~XCD)
#define PAD1  520              // cell capacity: Poisson(400) + 6 sigma
#define P1_WGS 1024
#define EPW1  (N_EDGES / P1_WGS)   // 6250 edges per WG, exact
#define ORD_STRIDE (NSETS * PAD1)  // 4160 edge refs per bucket (u16)

// ---------------- workspace layout (bytes) ----------------------------------
#define OFF_XL   0
#define OFF_H1   ((size_t)N_NODES * 16)                         // 1,600,000
#define OFF_H2   (OFF_H1 + (size_t)N_NODES * 48)                // 6,400,000
#define OFF_CUR  (OFF_H2 + (size_t)N_NODES * 112)               // 17,600,000: [NSETS*NBKT] int
#define OFF_PFXG ((OFF_CUR + (size_t)NSETS * NBKT * 4 + 255) & ~(size_t)255)   // [NBKT][64] int
#define OFF_ORDG ((OFF_PFXG + (size_t)NBKT * 64 * 4 + 255) & ~(size_t)255)     // [NBKT][ORD_STRIDE] u16
#define OFF_STR  ((OFF_ORDG + (size_t)NBKT * ORD_STRIDE * 2 + 255) & ~(size_t)255)
#define WS_SORT_NEEDED (OFF_STR + (size_t)NSETS * NBKT * PAD1 * 16)   // ~168 MB

// ---------------- kernel 1: xl[n,i] = sum_j gauges[n,j,i] * x[n,j] ----------
__global__ void xl_kernel(const float* __restrict__ x,
                          const float* __restrict__ gauges,
                          float* __restrict__ xl) {
    int n = blockIdx.x * blockDim.x + threadIdx.x;
    if (n >= N_NODES) return;
    float x0 = x[n * 3 + 0], x1 = x[n * 3 + 1], x2 = x[n * 3 + 2];
    const float* g = gauges + n * 9;
    float4 o;
    o.x = g[0] * x0 + g[3] * x1 + g[6] * x2;
    o.y = g[1] * x0 + g[4] * x1 + g[7] * x2;
    o.z = g[2] * x0 + g[5] * x1 + g[8] * x2;
    o.w = 0.f;
    ((float4*)xl)[n] = o;
}

// ---------------- bin: edges -> per-(set,bucket) strips ---------------------
// set = blockIdx&7 ~ XCD (perf heuristic only; correctness never depends on it)
__global__ __launch_bounds__(256) void bin_kernel(const int* __restrict__ ei,
                                                  const float* __restrict__ kv,
                                                  int* __restrict__ cur,
                                                  float4* __restrict__ strips) {
    int w = blockIdx.x, t = threadIdx.x;
    int s = w & (NSETS - 1);
    int e0 = w * EPW1;
    for (int e = e0 + t; e < e0 + EPW1; e += 256) {
        int src = ei[e];
        int d   = ei[N_EDGES + e];
        int b   = d / BKN;
        int dl  = d - b * BKN;             // 0..49
        float4 p;
        p.x = kv[e];
        p.y = kv[N_EDGES + e];
        p.z = kv[2 * N_EDGES + e];
        p.w = __int_as_float(src | (dl << 17));   // src < 2^17, dl in bits 17..22
        int cell = s * NBKT + b;
        int slot = atomicAdd(&cur[cell], 1);
        if (slot < PAD1) strips[(size_t)cell * PAD1 + slot] = p;
    }
}

// ---------------- conv1: sort bucket by node, wave-per-node register acc ----
__global__ __launch_bounds__(256) void conv1_sort(const int* __restrict__ cur,
                                                  const float4* __restrict__ strips,
                                                  const float4* __restrict__ xl,
                                                  float* __restrict__ h1,
                                                  unsigned short* __restrict__ ord_g,
                                                  int* __restrict__ pfx_g) {
    __shared__ int segpfx[NSETS + 1];
    __shared__ int ncnt[BKN];
    __shared__ int npfx[BKN + 1];
    __shared__ int ncur[BKN];
    __shared__ unsigned tmp[ORD_STRIDE];
    __shared__ unsigned short ord[ORD_STRIDE];
    int b = blockIdx.x, t = threadIdx.x;

    for (int i = t; i < BKN; i += 256) ncnt[i] = 0;
    if (t == 0) {
        int run = 0;
        for (int s = 0; s < NSETS; ++s) {
            segpfx[s] = run;
            int c = cur[s * NBKT + b];
            run += (c < PAD1 ? c : PAD1);
        }
        segpfx[NSETS] = run;
    }
    __syncthreads();
    int total = segpfx[NSETS];

    // phase A: read node tag (4B), count, stash
    for (int j = t; j < total; j += 256) {
        int s = 0;
#pragma unroll
        for (int k = 1; k < NSETS; ++k) s += (j >= segpfx[k]);
        int idx = j - segpfx[s];
        const float* cell = (const float*)&strips[((size_t)(s * NBKT + b)) * PAD1 + idx];
        unsigned pw = __float_as_uint(cell[3]);
        int dl = (pw >> 17) & 63;
        atomicAdd(&ncnt[dl], 1);
        tmp[j] = ((unsigned)dl << 16) | ((unsigned)s << 10) | (unsigned)idx;
    }
    __syncthreads();
    // phase B: prefix (tiny)
    if (t == 0) {
        int run = 0;
        for (int i = 0; i < BKN; ++i) { npfx[i] = run; ncur[i] = run; run += ncnt[i]; }
        npfx[BKN] = run;
    }
    __syncthreads();
    // phase C: place sorted refs
    for (int j = t; j < total; j += 256) {
        unsigned v = tmp[j];
        int slot = atomicAdd(&ncur[v >> 16], 1);
        ord[slot] = (unsigned short)(v & 0xFFFF);
    }
    __syncthreads();
    // persist sort for conv2
    for (int j = t; j < total; j += 256) ord_g[(size_t)b * ORD_STRIDE + j] = ord[j];
    for (int i = t; i <= BKN; i += 256) pfx_g[b * 64 + i] = npfx[i];

    // phase D: wave per node, register acc + shuffle reduce (R6-proven)
    int wave = t >> 6, lane = t & 63;
    for (int n = wave; n < BKN; n += 4) {
        int st = npfx[n], en = npfx[n + 1];
        float a[9];
#pragma unroll
        for (int c = 0; c < 9; ++c) a[c] = 0.f;
        for (int i = st + lane; i < en; i += 64) {
            unsigned short v = ord[i];
            int s = v >> 10, idx = v & 1023;
            float4 p = strips[((size_t)(s * NBKT + b)) * PAD1 + idx];
            float4 xs = xl[__float_as_uint(p.w) & 0x1FFFF];
            a[0] += p.x * xs.x; a[1] += p.y * xs.x; a[2] += p.z * xs.x;
            a[3] += p.x * xs.y; a[4] += p.y * xs.y; a[5] += p.z * xs.y;
            a[6] += p.x * xs.z; a[7] += p.y * xs.z; a[8] += p.z * xs.z;
        }
#pragma unroll
        for (int off = 32; off > 0; off >>= 1) {
#pragma unroll
            for (int c = 0; c < 9; ++c) a[c] += __shfl_xor(a[c], off, 64);
        }
        if (lane == 0) {
            float* r = h1 + (size_t)(b * BKN + n) * 12;
            ((float4*)r)[0] = make_float4(a[0], a[1], a[2], a[3]);
            ((float4*)r)[1] = make_float4(a[4], a[5], a[6], a[7]);
            ((float4*)r)[2] = make_float4(a[8], 0.f, 0.f, 0.f);
        }
    }
}

// ---------------- conv2: reuse conv1's sort, wave-per-node register acc -----
__global__ __launch_bounds__(256) void conv2_sort(const float4* __restrict__ strips,
                                                  const float* __restrict__ h1,
                                                  float* __restrict__ h2,
                                                  const unsigned short* __restrict__ ord_g,
                                                  const int* __restrict__ pfx_g) {
    __shared__ int npfx[BKN + 1];
    int b = blockIdx.x, t = threadIdx.x;
    for (int i = t; i <= BKN; i += 256) npfx[i] = pfx_g[b * 64 + i];
    __syncthreads();
    const unsigned short* ob = ord_g + (size_t)b * ORD_STRIDE;
    int wave = t >> 6, lane = t & 63;
    for (int n = wave; n < BKN; n += 4) {
        int st = npfx[n], en = npfx[n + 1];
        float a[27];
#pragma unroll
        for (int c = 0; c < 27; ++c) a[c] = 0.f;
        for (int i = st + lane; i < en; i += 64) {
            unsigned short v = ob[i];
            int s = v >> 10, idx = v & 1023;
            float4 p = strips[((size_t)(s * NBKT + b)) * PAD1 + idx];
            int src = __float_as_uint(p.w) & 0x1FFFF;
            const float4* hs = (const float4*)(h1 + (size_t)src * 12);
            float4 v0 = hs[0], v1 = hs[1], v2 = hs[2];
            float h[9] = {v0.x, v0.y, v0.z, v0.w, v1.x, v1.y, v1.z, v1.w, v2.x};
#pragma unroll
            for (int c = 0; c < 9; ++c) {
                a[c * 3 + 0] += p.x * h[c];
                a[c * 3 + 1] += p.y * h[c];
                a[c * 3 + 2] += p.z * h[c];
            }
        }
#pragma unroll
        for (int off = 32; off > 0; off >>= 1) {
#pragma unroll
            for (int c = 0; c < 27; ++c) a[c] += __shfl_xor(a[c], off, 64);
        }
        if (lane == 0) {
            float* r = h2 + (size_t)(b * BKN + n) * 28;
#pragma unroll
            for (int q = 0; q < 6; ++q)
                ((float4*)r)[q] = make_float4(a[q*4], a[q*4+1], a[q*4+2], a[q*4+3]);
            ((float4*)r)[6] = make_float4(a[24], a[25], a[26], 0.f);
        }
    }
}

// ---------------- last-resort atomic fallback (small ws) --------------------
__global__ void edge1_atomic(const int* __restrict__ ei,
                             const float* __restrict__ kv,
                             const float* __restrict__ xl,
                             float* __restrict__ h1) {
    int e = blockIdx.x * blockDim.x + threadIdx.x;
    if (e >= N_EDGES) return;
    int s = ei[e], d = ei[N_EDGES + e];
    float k0 = kv[e], k1 = kv[N_EDGES + e], k2 = kv[2 * N_EDGES + e];
    const float* xs = xl + (size_t)s * 4;
    float* hd = h1 + (size_t)d * 12;
#pragma unroll
    for (int c = 0; c < 3; ++c) {
        float v = xs[c];
        atomicAdd(hd + c * 3 + 0, k0 * v);
        atomicAdd(hd + c * 3 + 1, k1 * v);
        atomicAdd(hd + c * 3 + 2, k2 * v);
    }
}

__global__ void edge2_atomic(const int* __restrict__ ei,
                             const float* __restrict__ kv,
                             const float* __restrict__ h1,
                             float* __restrict__ h2) {
    int e = blockIdx.x * blockDim.x + threadIdx.x;
    if (e >= N_EDGES) return;
    int s = ei[e], d = ei[N_EDGES + e];
    float k0 = kv[e], k1 = kv[N_EDGES + e], k2 = kv[2 * N_EDGES + e];
    const float* hs = h1 + (size_t)s * 12;
    float* hd = h2 + (size_t)d * 28;
#pragma unroll
    for (int c = 0; c < 9; ++c) {
        float v = hs[c];
        atomicAdd(hd + c * 3 + 0, k0 * v);
        atomicAdd(hd + c * 3 + 1, k1 * v);
        atomicAdd(hd + c * 3 + 2, k2 * v);
    }
}

// ---------------- MLP 39 -> 256 (relu) -> 64 --------------------------------
__global__ __launch_bounds__(256) void mlp_kernel(const float* __restrict__ xl,
                                                  const float* __restrict__ h1,
                                                  const float* __restrict__ h2,
                                                  const float* __restrict__ W1,
                                                  const float* __restrict__ b1,
                                                  const float* __restrict__ W2,
                                                  const float* __restrict__ b2,
                                                  float* __restrict__ out) {
    __shared__ float f[NB][FEAT + 1];
    __shared__ float hmid[NB][HID];
    __shared__ float partial[4][NB][OUT];

    int t = threadIdx.x;
    int base = blockIdx.x * NB;

    for (int i = t; i < NB * FEAT; i += 256) {
        int m = i / FEAT, k = i % FEAT;
        int n = base + m;
        float v = 0.f;
        if (n < N_NODES) {
            if (k < 3)       v = xl[(size_t)n * 4 + k];
            else if (k < 12) v = h1[(size_t)n * 12 + (k - 3)];
            else             v = h2[(size_t)n * 28 + (k - 12)];
        }
        f[m][k] = v;
    }
    __syncthreads();

    float acc[NB];
    float bb = b1[t];
#pragma unroll
    for (int m = 0; m < NB; ++m) acc[m] = bb;
#pragma unroll
    for (int k = 0; k < FEAT; ++k) {
        float w = W1[k * HID + t];
#pragma unroll
        for (int m = 0; m < NB; ++m) acc[m] += f[m][k] * w;
    }
#pragma unroll
    for (int m = 0; m < NB; ++m) hmid[m][t] = fmaxf(acc[m], 0.f);
    __syncthreads();

    int o = t & 63, q = t >> 6;
    float p[NB];
#pragma unroll
    for (int m = 0; m < NB; ++m) p[m] = 0.f;
    for (int hh = 0; hh < 64; ++hh) {
        int h = q * 64 + hh;
        float w = W2[h * OUT + o];
#pragma unroll
        for (int m = 0; m < NB; ++m) p[m] += hmid[m][h] * w;
    }
#pragma unroll
    for (int m = 0; m < NB; ++m) partial[q][m][o] = p[m];
    __syncthreads();

    if (t < OUT) {
        float bo = b2[t];
        for (int m = 0; m < NB; ++m) {
            int n = base + m;
            if (n < N_NODES) {
                out[n * OUT + t] = partial[0][m][t] + partial[1][m][t] +
                                   partial[2][m][t] + partial[3][m][t] + bo;
            }
        }
    }
}

extern "C" void kernel_launch(void* const* d_in, const int* in_sizes, int n_in,
                              void* d_out, int out_size, void* d_ws, size_t ws_size,
                              hipStream_t stream) {
    const float* x      = (const float*)d_in[0];
    const float* gauges = (const float*)d_in[1];
    const float* kv     = (const float*)d_in[2];
    const float* W1     = (const float*)d_in[3];
    const float* b1     = (const float*)d_in[4];
    const float* W2     = (const float*)d_in[5];
    const float* b2     = (const float*)d_in[6];
    const int*   ei     = (const int*)d_in[7];
    float* out = (float*)d_out;

    char* ws = (char*)d_ws;
    float* xl = (float*)(ws + OFF_XL);
    float* h1 = (float*)(ws + OFF_H1);
    float* h2 = (float*)(ws + OFF_H2);

    const int EB = (N_EDGES + 255) / 256;

    xl_kernel<<<(N_NODES + 255) / 256, 256, 0, stream>>>(x, gauges, xl);

    if (ws_size >= WS_SORT_NEEDED) {
        // -------- set-keyed strips + in-LDS counting sort + register convs ---
        int*            cur   = (int*)(ws + OFF_CUR);
        int*            pfx_g = (int*)(ws + OFF_PFXG);
        unsigned short* ord_g = (unsigned short*)(ws + OFF_ORDG);
        float4*         strips = (float4*)(ws + OFF_STR);
        hipMemsetAsync(cur, 0, (size_t)NSETS * NBKT * 4, stream);
        bin_kernel<<<P1_WGS, 256, 0, stream>>>(ei, kv, cur, strips);
        conv1_sort<<<NBKT, 256, 0, stream>>>(cur, strips, (const float4*)xl, h1, ord_g, pfx_g);
        conv2_sort<<<NBKT, 256, 0, stream>>>(strips, h1, h2, ord_g, pfx_g);
    } else {
        // -------- last resort: global float atomics (proven Round 2) --------
        hipMemsetAsync(h1, 0, (size_t)N_NODES * (48 + 112), stream);
        edge1_atomic<<<EB, 256, 0, stream>>>(ei, kv, xl, h1);
        edge2_atomic<<<EB, 256, 0, stream>>>(ei, kv, h1, h2);
    }

    mlp_kernel<<<(N_NODES + NB - 1) / NB, 256, 0, stream>>>(xl, h1, h2, W1, b1, W2, b2, out);
}